// Round 8
// baseline (774.594 us; speedup 1.0000x reference)
//
#include <hip/hip_runtime.h>

// BlockSelfAttention: B=8, H=W=256, C=128, P=8 -> 8192 windows, L=64, 4 heads x d=32.
// R11 = R5 (green baseline, 436us attn) + three ZERO-NUMERICS-RISK scheduling deltas:
//  (1) P4 wout hi/lo fragments prefetched to registers during phase 3 (issued after b5)
//  (2) bias/gamma per-thread loads hoisted to kernel start (hide under phase-1 x loads)
//  (3) s_setprio(1) around phase-3 MFMA clusters (QK, PV) only — blocks independent
// No arithmetic value, order, or memory content changes. Expected absmax: 5.960464e-08.
//
// R5 structure: 512 threads = 8 waves, LDS 73728 -> 2 blocks/CU (two independent
// barrier domains). Full two-term bf16 hi/lo numerics (fp32-equivalent, RNE).
// LDS lifetime: A: X -> K -> P-scratch   B: Q -> VT -> O; K/Q/VT frags preloaded to
// registers between overwrites.
//
// Work split (wave w = 0..7):
//  P1 LN:    wave w owns pixel row w (8 px), 8 threads/px, 16 ch each
//  P2 QKV:   wave w owns col-tiles {w, w+8, w+16}, all 4 mi
//  P3 attn:  wave = (head h = w>>1, mi-half = w&1); swapped QK^T
//  P4 proj:  wave w owns out col-tile w, all 4 mi

typedef short    short8  __attribute__((ext_vector_type(8)));
typedef __bf16   bf16x8  __attribute__((ext_vector_type(8)));
typedef float    floatx4 __attribute__((ext_vector_type(4)));

#define LOG2E 1.44269504088896f
#define ATTN_SCALE 0.17677669529663687f   // 1/sqrt(32)

// Region A: X_hi@0 X_lo@17408 | K_hi@0 K_lo@17408 | P: wave w @ w*4608 (hi 2304 + lo 2304)
// Region B: Q_hi@0 Q_lo@17408 | VT_hi@0 (4 heads x 4608) VT_lo@18432 | O_hi@0 O_lo@17408
#define A_OFF 0
#define B_OFF 36864
#define SMEM_BYTES 73728

__device__ __forceinline__ unsigned short f2bf(float f) {
  return __builtin_bit_cast(unsigned short, (__bf16)f);   // RNE, fuses to v_cvt_pk_bf16_f32
}
__device__ __forceinline__ float bf2f(unsigned short h) {
  return __builtin_bit_cast(float, ((unsigned)h) << 16);
}
__device__ __forceinline__ unsigned pk2(float a, float b) {
  return (unsigned)f2bf(a) | ((unsigned)f2bf(b) << 16);
}

__device__ __forceinline__ floatx4 mfma_bf16(short8 a, short8 b, floatx4 c) {
  return __builtin_amdgcn_mfma_f32_16x16x32_bf16(
      __builtin_bit_cast(bf16x8, a), __builtin_bit_cast(bf16x8, b), c, 0, 0, 0);
}

// ws layout (unsigned short): [0,49152) wqkv_hi | [49152,65536) wout_hi
//                             [65536,114688) wqkv_lo | [114688,131072) wout_lo
__global__ void convert_weights(const float* __restrict__ ipw,
                                const float* __restrict__ opw,
                                unsigned short* __restrict__ ws) {
  int i = blockIdx.x * 256 + threadIdx.x;     // 0..65535
  float v = (i < 49152) ? ipw[i] : opw[i - 49152];
  unsigned short hi = f2bf(v);
  ws[i] = hi;
  ws[65536 + i] = f2bf(v - bf2f(hi));
}

__global__ __launch_bounds__(512, 4)
void attn_kernel(const float* __restrict__ x,
                 const float* __restrict__ ln_w,
                 const float* __restrict__ ln_b,
                 const float* __restrict__ in_proj_b,
                 const float* __restrict__ out_proj_b,
                 const float* __restrict__ gamma,
                 const unsigned short* __restrict__ wqkv_h,   // [384][128]
                 const unsigned short* __restrict__ wqkv_l,
                 const unsigned short* __restrict__ wout_h,   // [128][128]
                 const unsigned short* __restrict__ wout_l,
                 float* __restrict__ out) {
  __shared__ uint4 smem4[SMEM_BYTES / 16];
  char* smem = (char*)smem4;

  const int t    = threadIdx.x;
  const int lane = t & 63;
  const int ln   = lane & 15;     // MFMA row/col lane index
  const int hg   = lane >> 4;     // MFMA k-group / row-group
  const int w    = t >> 6;        // wave id 0..7

  const int win = blockIdx.x;
  const int bb = win >> 10, wh = (win >> 5) & 31, ww = win & 31;
  const size_t gbase = ((size_t)(bb * 256 + wh * 8) * 256 + (size_t)(ww * 8)) * 128;

  const floatx4 z4 = (floatx4){0.f, 0.f, 0.f, 0.f};

  // (2) Hoisted per-thread bias/gamma loads — values used in E1/E3/P4, issued now so
  // their latency hides under the phase-1 global x loads. Identical values.
  const float bq_e1 = in_proj_b[w * 16 + ln];
  const float bk_e1 = in_proj_b[128 + w * 16 + ln];
  const float bv_e3 = in_proj_b[256 + w * 16 + ln];
  const float bo_p4 = out_proj_b[w * 16 + ln];
  const float gm_p4 = gamma[w * 16 + ln];

  // ---------------- Phase 1: LayerNorm (fp32) -> X hi/lo bf16 in A ----------------
  {
    const int p = t >> 3, sub = t & 7;        // 8 threads per pixel, 16 ch each
    const int py = p >> 3, px = p & 7;
    const float* xp = x + gbase + (size_t)(py * 256 + px) * 128 + sub * 16;
    float4 va[4];
#pragma unroll
    for (int j = 0; j < 4; j++) va[j] = *(const float4*)(xp + j * 4);
    float s = 0.f, s2 = 0.f;
#pragma unroll
    for (int j = 0; j < 4; j++) {
      float4 a = va[j];
      s  += a.x + a.y + a.z + a.w;
      s2 += a.x * a.x + a.y * a.y + a.z * a.z + a.w * a.w;
    }
    s  += __shfl_xor(s, 1);  s  += __shfl_xor(s, 2);  s  += __shfl_xor(s, 4);
    s2 += __shfl_xor(s2, 1); s2 += __shfl_xor(s2, 2); s2 += __shfl_xor(s2, 4);
    const float mu = s * (1.f / 128.f);
    const float var = s2 * (1.f / 128.f) - mu * mu;
    const float rs = rsqrtf(var + 1e-5f);
#pragma unroll
    for (int j = 0; j < 4; j++) {
      const int c = sub * 16 + j * 4;
      float4 lw = *(const float4*)(ln_w + c);
      float4 lb = *(const float4*)(ln_b + c);
      float4 a = va[j];
      float o0 = (a.x - mu) * rs * lw.x + lb.x;
      float o1 = (a.y - mu) * rs * lw.y + lb.y;
      float o2 = (a.z - mu) * rs * lw.z + lb.z;
      float o3 = (a.w - mu) * rs * lw.w + lb.w;
      unsigned short h0 = f2bf(o0), h1 = f2bf(o1), h2 = f2bf(o2), h3 = f2bf(o3);
      uint2 hi = make_uint2((unsigned)h0 | ((unsigned)h1 << 16),
                            (unsigned)h2 | ((unsigned)h3 << 16));
      uint2 lo = make_uint2(pk2(o0 - bf2f(h0), o1 - bf2f(h1)),
                            pk2(o2 - bf2f(h2), o3 - bf2f(h3)));
      *(uint2*)(smem + A_OFF + (p * 136 + c) * 2) = hi;
      *(uint2*)(smem + A_OFF + 17408 + (p * 136 + c) * 2) = lo;
    }
  }
  __syncthreads();   // b0: X ready

  // ---------------- Phase 2: QKV = (Xh+Xl) @ (Wh+Wl)^T  (3 MFMAs/term) ----------------
  floatx4 acc[3][4];                          // j = {Q,K,V} tile, mi = row-tile
#pragma unroll
  for (int j = 0; j < 3; j++)
#pragma unroll
    for (int mi = 0; mi < 4; mi++) acc[j][mi] = z4;

#pragma unroll
  for (int kk = 0; kk < 4; kk++) {
    short8 ah[4], al[4];
#pragma unroll
    for (int mi = 0; mi < 4; mi++) {
      const int idx = ((mi * 16 + ln) * 136 + kk * 32 + hg * 8) * 2;
      ah[mi] = *(const short8*)(smem + A_OFF + idx);
      al[mi] = *(const short8*)(smem + A_OFF + 17408 + idx);
    }
#pragma unroll
    for (int j = 0; j < 3; j++) {
      const int widx = ((w + j * 8) * 16 + ln) * 128 + kk * 32 + hg * 8;
      short8 bh = *(const short8*)(wqkv_h + widx);
      short8 bl = *(const short8*)(wqkv_l + widx);
#pragma unroll
      for (int mi = 0; mi < 4; mi++) {
        acc[j][mi] = mfma_bf16(ah[mi], bl, acc[j][mi]);
        acc[j][mi] = mfma_bf16(al[mi], bh, acc[j][mi]);
        acc[j][mi] = mfma_bf16(ah[mi], bh, acc[j][mi]);
      }
    }
  }
  __syncthreads();   // b1: X reads done; A free for K, B free for Q

  // E1: +bias, split hi/lo; Q -> B, K -> A (b16 scatter, [l][d] layout for frag reads)
  {
    const float bq = bq_e1;
    const float bk = bk_e1;
    const int d = w * 16 + ln;
#pragma unroll
    for (int mi = 0; mi < 4; mi++)
#pragma unroll
      for (int r = 0; r < 4; r++) {
        const int l = mi * 16 + hg * 4 + r;
        const int idx = (l * 136 + d) * 2;
        const float vq = acc[0][mi][r] + bq;
        const unsigned short hq = f2bf(vq);
        *(unsigned short*)(smem + B_OFF + idx) = hq;
        *(unsigned short*)(smem + B_OFF + 17408 + idx) = f2bf(vq - bf2f(hq));
        const float vk = acc[1][mi][r] + bk;
        const unsigned short hk = f2bf(vk);
        *(unsigned short*)(smem + A_OFF + idx) = hk;
        *(unsigned short*)(smem + A_OFF + 17408 + idx) = f2bf(vk - bf2f(hk));
      }
  }
  __syncthreads();   // b2: Q,K complete

  // E2: preload K-frags (A) and Q-frags (B) to registers
  const int h   = w >> 1;                     // head
  const int mi0 = (w & 1) * 2;                // mi-half
  short8 kbh[4], kbl[4], qah[2], qal[2];
#pragma unroll
  for (int n2 = 0; n2 < 4; n2++) {
    const int idx = ((n2 * 16 + ln) * 136 + h * 32 + hg * 8) * 2;
    kbh[n2] = *(const short8*)(smem + A_OFF + idx);
    kbl[n2] = *(const short8*)(smem + A_OFF + 17408 + idx);
  }
#pragma unroll
  for (int m = 0; m < 2; m++) {
    const int idx = (((mi0 + m) * 16 + ln) * 136 + h * 32 + hg * 8) * 2;
    qah[m] = *(const short8*)(smem + B_OFF + idx);
    qal[m] = *(const short8*)(smem + B_OFF + 17408 + idx);
  }
  __syncthreads();   // b3: Q/K reads done; B free for VT

  // E3: V^T -> B (pk-paired b32 writes; per head [32 d][72 l], row stride 144B)
  {
    const float bv = bv_e3;
    const int dv = w * 16 + ln;
    char* vth = smem + B_OFF + (dv >> 5) * 4608 + (dv & 31) * 144;
    char* vtl = vth + 18432;
#pragma unroll
    for (int mi = 0; mi < 4; mi++) {
      const float v0 = acc[2][mi][0] + bv, v1 = acc[2][mi][1] + bv;
      const float v2 = acc[2][mi][2] + bv, v3 = acc[2][mi][3] + bv;
      const unsigned short h0 = f2bf(v0), h1 = f2bf(v1);
      const unsigned short h2 = f2bf(v2), h3 = f2bf(v3);
      const int lb = (mi * 16 + hg * 4) * 2;  // byte offset of l within row
      *(unsigned*)(vth + lb)     = (unsigned)h0 | ((unsigned)h1 << 16);
      *(unsigned*)(vth + lb + 4) = (unsigned)h2 | ((unsigned)h3 << 16);
      *(unsigned*)(vtl + lb)     = pk2(v0 - bf2f(h0), v1 - bf2f(h1));
      *(unsigned*)(vtl + lb + 4) = pk2(v2 - bf2f(h2), v3 - bf2f(h3));
    }
  }
  __syncthreads();   // b4: VT complete

  // E4: preload VT-frags to registers
  short8 vbh[2][2], vbl[2][2];
#pragma unroll
  for (int ni = 0; ni < 2; ni++)
#pragma unroll
    for (int k2 = 0; k2 < 2; k2++) {
      const int idx = h * 4608 + (ni * 16 + ln) * 144 + (k2 * 32 + hg * 8) * 2;
      vbh[ni][k2] = *(const short8*)(smem + B_OFF + idx);
      vbl[ni][k2] = *(const short8*)(smem + B_OFF + 18432 + idx);
    }
  __syncthreads();   // b5: all VT reads done; A free for P, B free for O

  // (1) Prefetch P4 out-proj weight fragments NOW — their ~200-900cy global latency
  // hides under the whole of phase 3. Read-only global data; values identical.
  short8 wpo_h[4], wpo_l[4];
#pragma unroll
  for (int kk = 0; kk < 4; kk++) {
    const int widx = (w * 16 + ln) * 128 + kk * 32 + hg * 8;
    wpo_h[kk] = *(const short8*)(wout_h + widx);
    wpo_l[kk] = *(const short8*)(wout_l + widx);
  }

  // ---------------- Phase 3: attention, swapped QK^T (s = K x Q) ----------------
  // s[n2][r]: q = mi*16 + ln (lane-local row!), k = n2*16 + hg*4 + r
  char* ph = smem + A_OFF + w * 4608;         // P_hi [16 q][36 uint], 144B row stride
  char* pl = ph + 2304;                       // P_lo
#pragma unroll
  for (int m = 0; m < 2; m++) {
    const int mi = mi0 + m;
    floatx4 s[4];
    __builtin_amdgcn_s_setprio(1);            // (3) favor MFMA wave during QK cluster
#pragma unroll
    for (int n2 = 0; n2 < 4; n2++) {
      s[n2] = mfma_bf16(kbh[n2], qal[m], z4);
      s[n2] = mfma_bf16(kbl[n2], qah[m], s[n2]);
      s[n2] = mfma_bf16(kbh[n2], qah[m], s[n2]);
      s[n2] = s[n2] * ATTN_SCALE;
    }
    __builtin_amdgcn_s_setprio(0);
    // softmax over k: 16 in-reg values + 2 cross-hg shuffles
    float mx = fmaxf(fmaxf(s[0][0], s[0][1]), fmaxf(s[0][2], s[0][3]));
    mx = fmaxf(mx, fmaxf(fmaxf(s[1][0], s[1][1]), fmaxf(s[1][2], s[1][3])));
    mx = fmaxf(mx, fmaxf(fmaxf(s[2][0], s[2][1]), fmaxf(s[2][2], s[2][3])));
    mx = fmaxf(mx, fmaxf(fmaxf(s[3][0], s[3][1]), fmaxf(s[3][2], s[3][3])));
    mx = fmaxf(mx, __shfl_xor(mx, 16));
    mx = fmaxf(mx, __shfl_xor(mx, 32));
    float sum = 0.f;
#pragma unroll
    for (int n2 = 0; n2 < 4; n2++)
#pragma unroll
      for (int r = 0; r < 4; r++) {
        const float e = exp2f((s[n2][r] - mx) * LOG2E);
        s[n2][r] = e;
        sum += e;
      }
    sum += __shfl_xor(sum, 16);
    sum += __shfl_xor(sum, 32);
    const float inv = 1.0f / sum;
    // P hi/lo pk-paired along k -> per-wave scratch in A
#pragma unroll
    for (int n2 = 0; n2 < 4; n2++) {
      const float p0 = s[n2][0] * inv, p1 = s[n2][1] * inv;
      const float p2 = s[n2][2] * inv, p3 = s[n2][3] * inv;
      const unsigned short h0 = f2bf(p0), h1 = f2bf(p1);
      const unsigned short h2 = f2bf(p2), h3 = f2bf(p3);
      const int cb = ln * 144 + (n2 * 8 + hg * 2) * 4;   // byte offset of uint col
      *(unsigned*)(ph + cb)     = (unsigned)h0 | ((unsigned)h1 << 16);
      *(unsigned*)(ph + cb + 4) = (unsigned)h2 | ((unsigned)h3 << 16);
      *(unsigned*)(pl + cb)     = pk2(p0 - bf2f(h0), p1 - bf2f(h1));
      *(unsigned*)(pl + cb + 4) = pk2(p2 - bf2f(h2), p3 - bf2f(h3));
    }
    short8 pah[2], pal[2];
#pragma unroll
    for (int k2 = 0; k2 < 2; k2++) {
      const int off = ln * 144 + k2 * 64 + hg * 16;
      pah[k2] = *(const short8*)(ph + off);
      pal[k2] = *(const short8*)(pl + off);
    }
    floatx4 oacc[2];
    oacc[0] = z4; oacc[1] = z4;
    __builtin_amdgcn_s_setprio(1);            // (3) favor MFMA wave during PV cluster
#pragma unroll
    for (int ni = 0; ni < 2; ni++)
#pragma unroll
      for (int k2 = 0; k2 < 2; k2++) {
        oacc[ni] = mfma_bf16(pal[k2], vbh[ni][k2], oacc[ni]);
        oacc[ni] = mfma_bf16(pah[k2], vbl[ni][k2], oacc[ni]);
        oacc[ni] = mfma_bf16(pah[k2], vbh[ni][k2], oacc[ni]);
      }
    __builtin_amdgcn_s_setprio(0);
    // O hi/lo -> B ([l][d] layout for phase-4 frag reads)
#pragma unroll
    for (int ni = 0; ni < 2; ni++)
#pragma unroll
      for (int r = 0; r < 4; r++) {
        const int l = mi * 16 + hg * 4 + r;
        const int d = h * 32 + ni * 16 + ln;
        const int idx = (l * 136 + d) * 2;
        const float v = oacc[ni][r];
        const unsigned short hv = f2bf(v);
        *(unsigned short*)(smem + B_OFF + idx) = hv;
        *(unsigned short*)(smem + B_OFF + 17408 + idx) = f2bf(v - bf2f(hv));
      }
  }
  __syncthreads();   // b6: O complete

  // ---------------- Phase 4: Y = (Oh+Ol) @ (Wh+Wl)^T, +bias, *gamma, store -------------
  floatx4 y[4];
#pragma unroll
  for (int mi = 0; mi < 4; mi++) y[mi] = z4;
#pragma unroll
  for (int kk = 0; kk < 4; kk++) {
    short8 oh[4], ol[4];
#pragma unroll
    for (int mi = 0; mi < 4; mi++) {
      const int idx = ((mi * 16 + ln) * 136 + kk * 32 + hg * 8) * 2;
      oh[mi] = *(const short8*)(smem + B_OFF + idx);
      ol[mi] = *(const short8*)(smem + B_OFF + 17408 + idx);
    }
    const short8 wbh = wpo_h[kk];             // prefetched during phase 3
    const short8 wbl = wpo_l[kk];
#pragma unroll
    for (int mi = 0; mi < 4; mi++) {
      y[mi] = mfma_bf16(ol[mi], wbh, y[mi]);
      y[mi] = mfma_bf16(oh[mi], wbl, y[mi]);
      y[mi] = mfma_bf16(oh[mi], wbh, y[mi]);
    }
  }
  {
    const int d = w * 16 + ln;
    const float bo = bo_p4;
    const float g = gm_p4;
#pragma unroll
    for (int mi = 0; mi < 4; mi++)
#pragma unroll
      for (int r = 0; r < 4; r++) {
        const int l = mi * 16 + hg * 4 + r;
        const int py = l >> 3, px = l & 7;
        out[gbase + (size_t)(py * 256 + px) * 128 + d] = (y[mi][r] + bo) * g;
      }
  }
}

extern "C" void kernel_launch(void* const* d_in, const int* in_sizes, int n_in,
                              void* d_out, int out_size, void* d_ws, size_t ws_size,
                              hipStream_t stream) {
  const float* x     = (const float*)d_in[0];
  const float* ln_w  = (const float*)d_in[1];
  const float* ln_b  = (const float*)d_in[2];
  const float* ipw   = (const float*)d_in[3];
  const float* ipb   = (const float*)d_in[4];
  const float* opw   = (const float*)d_in[5];
  const float* opb   = (const float*)d_in[6];
  const float* gamma = (const float*)d_in[7];
  unsigned short* wbf = (unsigned short*)d_ws;

  convert_weights<<<256, 256, 0, stream>>>(ipw, opw, wbf);
  attn_kernel<<<8192, 512, 0, stream>>>(x, ln_w, ln_b, ipb, opb, gamma,
                                        wbf, wbf + 65536,          // wqkv hi/lo
                                        wbf + 49152, wbf + 114688, // wout hi/lo
                                        (float*)d_out);
}

// Round 9
// 707.990 us; speedup vs baseline: 1.0941x; 1.0941x over previous
//
#include <hip/hip_runtime.h>

// BlockSelfAttention: B=8, H=W=256, C=128, P=8 -> 8192 windows, L=64, 4 heads x d=32.
// R12 = R5 (green baseline, 436us attn) + ONE delta: s_setprio(1/0) around the two
// phase-3 MFMA clusters (QK^T, PV). No other changes — R11's weight prefetch caused
// a 426MB scratch spill (WRITE_SIZE 262144->688128) and is removed; bias hoisting
// removed (nil value). setprio costs no registers -> no spill; m191 regime (+4-7%).
// Health checks for this round: WRITE_SIZE == 262144, VGPR == 60, absmax <= ~1.5e-7.
//
// R5 structure: 512 threads = 8 waves, LDS 73728 -> 2 blocks/CU (two independent
// barrier domains). Full two-term bf16 hi/lo numerics (fp32-equivalent, RNE).
// LDS lifetime: A: X -> K -> P-scratch   B: Q -> VT -> O; K/Q/VT frags preloaded to
// registers between overwrites.
//
// Work split (wave w = 0..7):
//  P1 LN:    wave w owns pixel row w (8 px), 8 threads/px, 16 ch each
//  P2 QKV:   wave w owns col-tiles {w, w+8, w+16}, all 4 mi
//  P3 attn:  wave = (head h = w>>1, mi-half = w&1); swapped QK^T
//  P4 proj:  wave w owns out col-tile w, all 4 mi

typedef short    short8  __attribute__((ext_vector_type(8)));
typedef __bf16   bf16x8  __attribute__((ext_vector_type(8)));
typedef float    floatx4 __attribute__((ext_vector_type(4)));

#define LOG2E 1.44269504088896f
#define ATTN_SCALE 0.17677669529663687f   // 1/sqrt(32)

// Region A: X_hi@0 X_lo@17408 | K_hi@0 K_lo@17408 | P: wave w @ w*4608 (hi 2304 + lo 2304)
// Region B: Q_hi@0 Q_lo@17408 | VT_hi@0 (4 heads x 4608) VT_lo@18432 | O_hi@0 O_lo@17408
#define A_OFF 0
#define B_OFF 36864
#define SMEM_BYTES 73728

__device__ __forceinline__ unsigned short f2bf(float f) {
  return __builtin_bit_cast(unsigned short, (__bf16)f);   // RNE, fuses to v_cvt_pk_bf16_f32
}
__device__ __forceinline__ float bf2f(unsigned short h) {
  return __builtin_bit_cast(float, ((unsigned)h) << 16);
}
__device__ __forceinline__ unsigned pk2(float a, float b) {
  return (unsigned)f2bf(a) | ((unsigned)f2bf(b) << 16);
}

__device__ __forceinline__ floatx4 mfma_bf16(short8 a, short8 b, floatx4 c) {
  return __builtin_amdgcn_mfma_f32_16x16x32_bf16(
      __builtin_bit_cast(bf16x8, a), __builtin_bit_cast(bf16x8, b), c, 0, 0, 0);
}

// ws layout (unsigned short): [0,49152) wqkv_hi | [49152,65536) wout_hi
//                             [65536,114688) wqkv_lo | [114688,131072) wout_lo
__global__ void convert_weights(const float* __restrict__ ipw,
                                const float* __restrict__ opw,
                                unsigned short* __restrict__ ws) {
  int i = blockIdx.x * 256 + threadIdx.x;     // 0..65535
  float v = (i < 49152) ? ipw[i] : opw[i - 49152];
  unsigned short hi = f2bf(v);
  ws[i] = hi;
  ws[65536 + i] = f2bf(v - bf2f(hi));
}

__global__ __launch_bounds__(512, 4)
void attn_kernel(const float* __restrict__ x,
                 const float* __restrict__ ln_w,
                 const float* __restrict__ ln_b,
                 const float* __restrict__ in_proj_b,
                 const float* __restrict__ out_proj_b,
                 const float* __restrict__ gamma,
                 const unsigned short* __restrict__ wqkv_h,   // [384][128]
                 const unsigned short* __restrict__ wqkv_l,
                 const unsigned short* __restrict__ wout_h,   // [128][128]
                 const unsigned short* __restrict__ wout_l,
                 float* __restrict__ out) {
  __shared__ uint4 smem4[SMEM_BYTES / 16];
  char* smem = (char*)smem4;

  const int t    = threadIdx.x;
  const int lane = t & 63;
  const int ln   = lane & 15;     // MFMA row/col lane index
  const int hg   = lane >> 4;     // MFMA k-group / row-group
  const int w    = t >> 6;        // wave id 0..7

  const int win = blockIdx.x;
  const int bb = win >> 10, wh = (win >> 5) & 31, ww = win & 31;
  const size_t gbase = ((size_t)(bb * 256 + wh * 8) * 256 + (size_t)(ww * 8)) * 128;

  const floatx4 z4 = (floatx4){0.f, 0.f, 0.f, 0.f};

  // ---------------- Phase 1: LayerNorm (fp32) -> X hi/lo bf16 in A ----------------
  {
    const int p = t >> 3, sub = t & 7;        // 8 threads per pixel, 16 ch each
    const int py = p >> 3, px = p & 7;
    const float* xp = x + gbase + (size_t)(py * 256 + px) * 128 + sub * 16;
    float4 va[4];
#pragma unroll
    for (int j = 0; j < 4; j++) va[j] = *(const float4*)(xp + j * 4);
    float s = 0.f, s2 = 0.f;
#pragma unroll
    for (int j = 0; j < 4; j++) {
      float4 a = va[j];
      s  += a.x + a.y + a.z + a.w;
      s2 += a.x * a.x + a.y * a.y + a.z * a.z + a.w * a.w;
    }
    s  += __shfl_xor(s, 1);  s  += __shfl_xor(s, 2);  s  += __shfl_xor(s, 4);
    s2 += __shfl_xor(s2, 1); s2 += __shfl_xor(s2, 2); s2 += __shfl_xor(s2, 4);
    const float mu = s * (1.f / 128.f);
    const float var = s2 * (1.f / 128.f) - mu * mu;
    const float rs = rsqrtf(var + 1e-5f);
#pragma unroll
    for (int j = 0; j < 4; j++) {
      const int c = sub * 16 + j * 4;
      float4 lw = *(const float4*)(ln_w + c);
      float4 lb = *(const float4*)(ln_b + c);
      float4 a = va[j];
      float o0 = (a.x - mu) * rs * lw.x + lb.x;
      float o1 = (a.y - mu) * rs * lw.y + lb.y;
      float o2 = (a.z - mu) * rs * lw.z + lb.z;
      float o3 = (a.w - mu) * rs * lw.w + lb.w;
      unsigned short h0 = f2bf(o0), h1 = f2bf(o1), h2 = f2bf(o2), h3 = f2bf(o3);
      uint2 hi = make_uint2((unsigned)h0 | ((unsigned)h1 << 16),
                            (unsigned)h2 | ((unsigned)h3 << 16));
      uint2 lo = make_uint2(pk2(o0 - bf2f(h0), o1 - bf2f(h1)),
                            pk2(o2 - bf2f(h2), o3 - bf2f(h3)));
      *(uint2*)(smem + A_OFF + (p * 136 + c) * 2) = hi;
      *(uint2*)(smem + A_OFF + 17408 + (p * 136 + c) * 2) = lo;
    }
  }
  __syncthreads();   // b0: X ready

  // ---------------- Phase 2: QKV = (Xh+Xl) @ (Wh+Wl)^T  (3 MFMAs/term) ----------------
  floatx4 acc[3][4];                          // j = {Q,K,V} tile, mi = row-tile
#pragma unroll
  for (int j = 0; j < 3; j++)
#pragma unroll
    for (int mi = 0; mi < 4; mi++) acc[j][mi] = z4;

#pragma unroll
  for (int kk = 0; kk < 4; kk++) {
    short8 ah[4], al[4];
#pragma unroll
    for (int mi = 0; mi < 4; mi++) {
      const int idx = ((mi * 16 + ln) * 136 + kk * 32 + hg * 8) * 2;
      ah[mi] = *(const short8*)(smem + A_OFF + idx);
      al[mi] = *(const short8*)(smem + A_OFF + 17408 + idx);
    }
#pragma unroll
    for (int j = 0; j < 3; j++) {
      const int widx = ((w + j * 8) * 16 + ln) * 128 + kk * 32 + hg * 8;
      short8 bh = *(const short8*)(wqkv_h + widx);
      short8 bl = *(const short8*)(wqkv_l + widx);
#pragma unroll
      for (int mi = 0; mi < 4; mi++) {
        acc[j][mi] = mfma_bf16(ah[mi], bl, acc[j][mi]);
        acc[j][mi] = mfma_bf16(al[mi], bh, acc[j][mi]);
        acc[j][mi] = mfma_bf16(ah[mi], bh, acc[j][mi]);
      }
    }
  }
  __syncthreads();   // b1: X reads done; A free for K, B free for Q

  // E1: +bias, split hi/lo; Q -> B, K -> A (b16 scatter, [l][d] layout for frag reads)
  {
    const float bq = in_proj_b[w * 16 + ln];
    const float bk = in_proj_b[128 + w * 16 + ln];
    const int d = w * 16 + ln;
#pragma unroll
    for (int mi = 0; mi < 4; mi++)
#pragma unroll
      for (int r = 0; r < 4; r++) {
        const int l = mi * 16 + hg * 4 + r;
        const int idx = (l * 136 + d) * 2;
        const float vq = acc[0][mi][r] + bq;
        const unsigned short hq = f2bf(vq);
        *(unsigned short*)(smem + B_OFF + idx) = hq;
        *(unsigned short*)(smem + B_OFF + 17408 + idx) = f2bf(vq - bf2f(hq));
        const float vk = acc[1][mi][r] + bk;
        const unsigned short hk = f2bf(vk);
        *(unsigned short*)(smem + A_OFF + idx) = hk;
        *(unsigned short*)(smem + A_OFF + 17408 + idx) = f2bf(vk - bf2f(hk));
      }
  }
  __syncthreads();   // b2: Q,K complete

  // E2: preload K-frags (A) and Q-frags (B) to registers
  const int h   = w >> 1;                     // head
  const int mi0 = (w & 1) * 2;                // mi-half
  short8 kbh[4], kbl[4], qah[2], qal[2];
#pragma unroll
  for (int n2 = 0; n2 < 4; n2++) {
    const int idx = ((n2 * 16 + ln) * 136 + h * 32 + hg * 8) * 2;
    kbh[n2] = *(const short8*)(smem + A_OFF + idx);
    kbl[n2] = *(const short8*)(smem + A_OFF + 17408 + idx);
  }
#pragma unroll
  for (int m = 0; m < 2; m++) {
    const int idx = (((mi0 + m) * 16 + ln) * 136 + h * 32 + hg * 8) * 2;
    qah[m] = *(const short8*)(smem + B_OFF + idx);
    qal[m] = *(const short8*)(smem + B_OFF + 17408 + idx);
  }
  __syncthreads();   // b3: Q/K reads done; B free for VT

  // E3: V^T -> B (pk-paired b32 writes; per head [32 d][72 l], row stride 144B)
  {
    const float bv = in_proj_b[256 + w * 16 + ln];
    const int dv = w * 16 + ln;
    char* vth = smem + B_OFF + (dv >> 5) * 4608 + (dv & 31) * 144;
    char* vtl = vth + 18432;
#pragma unroll
    for (int mi = 0; mi < 4; mi++) {
      const float v0 = acc[2][mi][0] + bv, v1 = acc[2][mi][1] + bv;
      const float v2 = acc[2][mi][2] + bv, v3 = acc[2][mi][3] + bv;
      const unsigned short h0 = f2bf(v0), h1 = f2bf(v1);
      const unsigned short h2 = f2bf(v2), h3 = f2bf(v3);
      const int lb = (mi * 16 + hg * 4) * 2;  // byte offset of l within row
      *(unsigned*)(vth + lb)     = (unsigned)h0 | ((unsigned)h1 << 16);
      *(unsigned*)(vth + lb + 4) = (unsigned)h2 | ((unsigned)h3 << 16);
      *(unsigned*)(vtl + lb)     = pk2(v0 - bf2f(h0), v1 - bf2f(h1));
      *(unsigned*)(vtl + lb + 4) = pk2(v2 - bf2f(h2), v3 - bf2f(h3));
    }
  }
  __syncthreads();   // b4: VT complete

  // E4: preload VT-frags to registers
  short8 vbh[2][2], vbl[2][2];
#pragma unroll
  for (int ni = 0; ni < 2; ni++)
#pragma unroll
    for (int k2 = 0; k2 < 2; k2++) {
      const int idx = h * 4608 + (ni * 16 + ln) * 144 + (k2 * 32 + hg * 8) * 2;
      vbh[ni][k2] = *(const short8*)(smem + B_OFF + idx);
      vbl[ni][k2] = *(const short8*)(smem + B_OFF + 18432 + idx);
    }
  __syncthreads();   // b5: all VT reads done; A free for P, B free for O

  // ---------------- Phase 3: attention, swapped QK^T (s = K x Q) ----------------
  // s[n2][r]: q = mi*16 + ln (lane-local row!), k = n2*16 + hg*4 + r
  char* ph = smem + A_OFF + w * 4608;         // P_hi [16 q][36 uint], 144B row stride
  char* pl = ph + 2304;                       // P_lo
#pragma unroll
  for (int m = 0; m < 2; m++) {
    const int mi = mi0 + m;
    floatx4 s[4];
    __builtin_amdgcn_s_setprio(1);            // favor this wave's QK MFMA cluster
#pragma unroll
    for (int n2 = 0; n2 < 4; n2++) {
      s[n2] = mfma_bf16(kbh[n2], qal[m], z4);
      s[n2] = mfma_bf16(kbl[n2], qah[m], s[n2]);
      s[n2] = mfma_bf16(kbh[n2], qah[m], s[n2]);
      s[n2] = s[n2] * ATTN_SCALE;
    }
    __builtin_amdgcn_s_setprio(0);
    // softmax over k: 16 in-reg values + 2 cross-hg shuffles
    float mx = fmaxf(fmaxf(s[0][0], s[0][1]), fmaxf(s[0][2], s[0][3]));
    mx = fmaxf(mx, fmaxf(fmaxf(s[1][0], s[1][1]), fmaxf(s[1][2], s[1][3])));
    mx = fmaxf(mx, fmaxf(fmaxf(s[2][0], s[2][1]), fmaxf(s[2][2], s[2][3])));
    mx = fmaxf(mx, fmaxf(fmaxf(s[3][0], s[3][1]), fmaxf(s[3][2], s[3][3])));
    mx = fmaxf(mx, __shfl_xor(mx, 16));
    mx = fmaxf(mx, __shfl_xor(mx, 32));
    float sum = 0.f;
#pragma unroll
    for (int n2 = 0; n2 < 4; n2++)
#pragma unroll
      for (int r = 0; r < 4; r++) {
        const float e = exp2f((s[n2][r] - mx) * LOG2E);
        s[n2][r] = e;
        sum += e;
      }
    sum += __shfl_xor(sum, 16);
    sum += __shfl_xor(sum, 32);
    const float inv = 1.0f / sum;
    // P hi/lo pk-paired along k -> per-wave scratch in A
#pragma unroll
    for (int n2 = 0; n2 < 4; n2++) {
      const float p0 = s[n2][0] * inv, p1 = s[n2][1] * inv;
      const float p2 = s[n2][2] * inv, p3 = s[n2][3] * inv;
      const unsigned short h0 = f2bf(p0), h1 = f2bf(p1);
      const unsigned short h2 = f2bf(p2), h3 = f2bf(p3);
      const int cb = ln * 144 + (n2 * 8 + hg * 2) * 4;   // byte offset of uint col
      *(unsigned*)(ph + cb)     = (unsigned)h0 | ((unsigned)h1 << 16);
      *(unsigned*)(ph + cb + 4) = (unsigned)h2 | ((unsigned)h3 << 16);
      *(unsigned*)(pl + cb)     = pk2(p0 - bf2f(h0), p1 - bf2f(h1));
      *(unsigned*)(pl + cb + 4) = pk2(p2 - bf2f(h2), p3 - bf2f(h3));
    }
    short8 pah[2], pal[2];
#pragma unroll
    for (int k2 = 0; k2 < 2; k2++) {
      const int off = ln * 144 + k2 * 64 + hg * 16;
      pah[k2] = *(const short8*)(ph + off);
      pal[k2] = *(const short8*)(pl + off);
    }
    floatx4 oacc[2];
    oacc[0] = z4; oacc[1] = z4;
    __builtin_amdgcn_s_setprio(1);            // favor this wave's PV MFMA cluster
#pragma unroll
    for (int ni = 0; ni < 2; ni++)
#pragma unroll
      for (int k2 = 0; k2 < 2; k2++) {
        oacc[ni] = mfma_bf16(pal[k2], vbh[ni][k2], oacc[ni]);
        oacc[ni] = mfma_bf16(pah[k2], vbl[ni][k2], oacc[ni]);
        oacc[ni] = mfma_bf16(pah[k2], vbh[ni][k2], oacc[ni]);
      }
    __builtin_amdgcn_s_setprio(0);
    // O hi/lo -> B ([l][d] layout for phase-4 frag reads)
#pragma unroll
    for (int ni = 0; ni < 2; ni++)
#pragma unroll
      for (int r = 0; r < 4; r++) {
        const int l = mi * 16 + hg * 4 + r;
        const int d = h * 32 + ni * 16 + ln;
        const int idx = (l * 136 + d) * 2;
        const float v = oacc[ni][r];
        const unsigned short hv = f2bf(v);
        *(unsigned short*)(smem + B_OFF + idx) = hv;
        *(unsigned short*)(smem + B_OFF + 17408 + idx) = f2bf(v - bf2f(hv));
      }
  }
  __syncthreads();   // b6: O complete

  // ---------------- Phase 4: Y = (Oh+Ol) @ (Wh+Wl)^T, +bias, *gamma, store -------------
  floatx4 y[4];
#pragma unroll
  for (int mi = 0; mi < 4; mi++) y[mi] = z4;
#pragma unroll
  for (int kk = 0; kk < 4; kk++) {
    short8 oh[4], ol[4];
#pragma unroll
    for (int mi = 0; mi < 4; mi++) {
      const int idx = ((mi * 16 + ln) * 136 + kk * 32 + hg * 8) * 2;
      oh[mi] = *(const short8*)(smem + B_OFF + idx);
      ol[mi] = *(const short8*)(smem + B_OFF + 17408 + idx);
    }
    const int widx = (w * 16 + ln) * 128 + kk * 32 + hg * 8;
    short8 wbh = *(const short8*)(wout_h + widx);
    short8 wbl = *(const short8*)(wout_l + widx);
#pragma unroll
    for (int mi = 0; mi < 4; mi++) {
      y[mi] = mfma_bf16(ol[mi], wbh, y[mi]);
      y[mi] = mfma_bf16(oh[mi], wbl, y[mi]);
      y[mi] = mfma_bf16(oh[mi], wbh, y[mi]);
    }
  }
  {
    const int d = w * 16 + ln;
    const float bo = out_proj_b[d];
    const float g = gamma[d];
#pragma unroll
    for (int mi = 0; mi < 4; mi++)
#pragma unroll
      for (int r = 0; r < 4; r++) {
        const int l = mi * 16 + hg * 4 + r;
        const int py = l >> 3, px = l & 7;
        out[gbase + (size_t)(py * 256 + px) * 128 + d] = (y[mi][r] + bo) * g;
      }
  }
}

extern "C" void kernel_launch(void* const* d_in, const int* in_sizes, int n_in,
                              void* d_out, int out_size, void* d_ws, size_t ws_size,
                              hipStream_t stream) {
  const float* x     = (const float*)d_in[0];
  const float* ln_w  = (const float*)d_in[1];
  const float* ln_b  = (const float*)d_in[2];
  const float* ipw   = (const float*)d_in[3];
  const float* ipb   = (const float*)d_in[4];
  const float* opw   = (const float*)d_in[5];
  const float* opb   = (const float*)d_in[6];
  const float* gamma = (const float*)d_in[7];
  unsigned short* wbf = (unsigned short*)d_ws;

  convert_weights<<<256, 256, 0, stream>>>(ipw, opw, wbf);
  attn_kernel<<<8192, 512, 0, stream>>>(x, ln_w, ln_b, ipb, opb, gamma,
                                        wbf, wbf + 65536,          // wqkv hi/lo
                                        wbf + 49152, wbf + 114688, // wout hi/lo
                                        (float*)d_out);
}

// Round 10
// 693.135 us; speedup vs baseline: 1.1175x; 1.0214x over previous
//
#include <hip/hip_runtime.h>

// BlockSelfAttention: B=8, H=W=256, C=128, P=8 -> 8192 windows, L=64, 4 heads x d=32.
// FINAL = R5 byte-exact (best green: 698.7us bench, 436us attn, absmax 5.960464e-08).
// R12's setprio measured -1.5% (no wave role diversity in barrier-locked blocks) and
// is dropped. Session ladder: 1027 -> 699 us (+47%), via 2-blocks/CU barrier-domain
// overlap (R5). Remaining levers verified closed: 3 blocks/CU (LDS: K+VT >= 70KB),
// 32x32 shapes / packed epilogues (numerics-fragile, 0/4), reg prefetch (spills at
// VGPR 60 budget), setprio (neutral-negative), bank-conflict stride (alignment-pinned).
//
// R5: barrier-domain attack. 512 threads = 8 waves, LDS 73728 -> 2 blocks/CU so two
// independent barrier domains overlap each other's drains. Full two-term bf16 hi/lo
// numerics preserved (fp32-equivalent, RNE via native casts -> v_cvt_pk_bf16_f32).
//
// LDS lifetime sequencing (two 36864B ping-pong regions):
//   A: X (LN out) -> K -> P-scratch     B: Q -> VT -> O
// Fragments for phase 3 (K,Q,VT) are preloaded to REGISTERS between overwrites.
//
// Work split (wave w = 0..7):
//  P1 LN:    wave w owns pixel row w (8 px), 8 threads/px, 16 ch each
//  P2 QKV:   wave w owns col-tiles {w, w+8, w+16} (one Q, one K, one V tile), all 4 mi
//            -> every weight fragment read exactly once per block
//  P3 attn:  wave = (head h = w>>1, mi-half = w&1), 2 mi-tiles each; swapped QK^T
//  P4 proj:  wave w owns out col-tile w, all 4 mi

typedef short    short8  __attribute__((ext_vector_type(8)));
typedef __bf16   bf16x8  __attribute__((ext_vector_type(8)));
typedef float    floatx4 __attribute__((ext_vector_type(4)));

#define LOG2E 1.44269504088896f
#define ATTN_SCALE 0.17677669529663687f   // 1/sqrt(32)

// Region A: X_hi@0 X_lo@17408 | K_hi@0 K_lo@17408 | P: wave w @ w*4608 (hi 2304 + lo 2304)
// Region B: Q_hi@0 Q_lo@17408 | VT_hi@0 (4 heads x 4608) VT_lo@18432 | O_hi@0 O_lo@17408
#define A_OFF 0
#define B_OFF 36864
#define SMEM_BYTES 73728

__device__ __forceinline__ unsigned short f2bf(float f) {
  return __builtin_bit_cast(unsigned short, (__bf16)f);   // RNE, fuses to v_cvt_pk_bf16_f32
}
__device__ __forceinline__ float bf2f(unsigned short h) {
  return __builtin_bit_cast(float, ((unsigned)h) << 16);
}
__device__ __forceinline__ unsigned pk2(float a, float b) {
  return (unsigned)f2bf(a) | ((unsigned)f2bf(b) << 16);
}

__device__ __forceinline__ floatx4 mfma_bf16(short8 a, short8 b, floatx4 c) {
  return __builtin_amdgcn_mfma_f32_16x16x32_bf16(
      __builtin_bit_cast(bf16x8, a), __builtin_bit_cast(bf16x8, b), c, 0, 0, 0);
}

// ws layout (unsigned short): [0,49152) wqkv_hi | [49152,65536) wout_hi
//                             [65536,114688) wqkv_lo | [114688,131072) wout_lo
__global__ void convert_weights(const float* __restrict__ ipw,
                                const float* __restrict__ opw,
                                unsigned short* __restrict__ ws) {
  int i = blockIdx.x * 256 + threadIdx.x;     // 0..65535
  float v = (i < 49152) ? ipw[i] : opw[i - 49152];
  unsigned short hi = f2bf(v);
  ws[i] = hi;
  ws[65536 + i] = f2bf(v - bf2f(hi));
}

__global__ __launch_bounds__(512, 4)
void attn_kernel(const float* __restrict__ x,
                 const float* __restrict__ ln_w,
                 const float* __restrict__ ln_b,
                 const float* __restrict__ in_proj_b,
                 const float* __restrict__ out_proj_b,
                 const float* __restrict__ gamma,
                 const unsigned short* __restrict__ wqkv_h,   // [384][128]
                 const unsigned short* __restrict__ wqkv_l,
                 const unsigned short* __restrict__ wout_h,   // [128][128]
                 const unsigned short* __restrict__ wout_l,
                 float* __restrict__ out) {
  __shared__ uint4 smem4[SMEM_BYTES / 16];
  char* smem = (char*)smem4;

  const int t    = threadIdx.x;
  const int lane = t & 63;
  const int ln   = lane & 15;     // MFMA row/col lane index
  const int hg   = lane >> 4;     // MFMA k-group / row-group
  const int w    = t >> 6;        // wave id 0..7

  const int win = blockIdx.x;
  const int bb = win >> 10, wh = (win >> 5) & 31, ww = win & 31;
  const size_t gbase = ((size_t)(bb * 256 + wh * 8) * 256 + (size_t)(ww * 8)) * 128;

  const floatx4 z4 = (floatx4){0.f, 0.f, 0.f, 0.f};

  // ---------------- Phase 1: LayerNorm (fp32) -> X hi/lo bf16 in A ----------------
  {
    const int p = t >> 3, sub = t & 7;        // 8 threads per pixel, 16 ch each
    const int py = p >> 3, px = p & 7;
    const float* xp = x + gbase + (size_t)(py * 256 + px) * 128 + sub * 16;
    float4 va[4];
#pragma unroll
    for (int j = 0; j < 4; j++) va[j] = *(const float4*)(xp + j * 4);
    float s = 0.f, s2 = 0.f;
#pragma unroll
    for (int j = 0; j < 4; j++) {
      float4 a = va[j];
      s  += a.x + a.y + a.z + a.w;
      s2 += a.x * a.x + a.y * a.y + a.z * a.z + a.w * a.w;
    }
    s  += __shfl_xor(s, 1);  s  += __shfl_xor(s, 2);  s  += __shfl_xor(s, 4);
    s2 += __shfl_xor(s2, 1); s2 += __shfl_xor(s2, 2); s2 += __shfl_xor(s2, 4);
    const float mu = s * (1.f / 128.f);
    const float var = s2 * (1.f / 128.f) - mu * mu;
    const float rs = rsqrtf(var + 1e-5f);
#pragma unroll
    for (int j = 0; j < 4; j++) {
      const int c = sub * 16 + j * 4;
      float4 lw = *(const float4*)(ln_w + c);
      float4 lb = *(const float4*)(ln_b + c);
      float4 a = va[j];
      float o0 = (a.x - mu) * rs * lw.x + lb.x;
      float o1 = (a.y - mu) * rs * lw.y + lb.y;
      float o2 = (a.z - mu) * rs * lw.z + lb.z;
      float o3 = (a.w - mu) * rs * lw.w + lb.w;
      unsigned short h0 = f2bf(o0), h1 = f2bf(o1), h2 = f2bf(o2), h3 = f2bf(o3);
      uint2 hi = make_uint2((unsigned)h0 | ((unsigned)h1 << 16),
                            (unsigned)h2 | ((unsigned)h3 << 16));
      uint2 lo = make_uint2(pk2(o0 - bf2f(h0), o1 - bf2f(h1)),
                            pk2(o2 - bf2f(h2), o3 - bf2f(h3)));
      *(uint2*)(smem + A_OFF + (p * 136 + c) * 2) = hi;
      *(uint2*)(smem + A_OFF + 17408 + (p * 136 + c) * 2) = lo;
    }
  }
  __syncthreads();   // b0: X ready

  // ---------------- Phase 2: QKV = (Xh+Xl) @ (Wh+Wl)^T  (3 MFMAs/term) ----------------
  floatx4 acc[3][4];                          // j = {Q,K,V} tile, mi = row-tile
#pragma unroll
  for (int j = 0; j < 3; j++)
#pragma unroll
    for (int mi = 0; mi < 4; mi++) acc[j][mi] = z4;

#pragma unroll
  for (int kk = 0; kk < 4; kk++) {
    short8 ah[4], al[4];
#pragma unroll
    for (int mi = 0; mi < 4; mi++) {
      const int idx = ((mi * 16 + ln) * 136 + kk * 32 + hg * 8) * 2;
      ah[mi] = *(const short8*)(smem + A_OFF + idx);
      al[mi] = *(const short8*)(smem + A_OFF + 17408 + idx);
    }
#pragma unroll
    for (int j = 0; j < 3; j++) {
      const int widx = ((w + j * 8) * 16 + ln) * 128 + kk * 32 + hg * 8;
      short8 bh = *(const short8*)(wqkv_h + widx);
      short8 bl = *(const short8*)(wqkv_l + widx);
#pragma unroll
      for (int mi = 0; mi < 4; mi++) {
        acc[j][mi] = mfma_bf16(ah[mi], bl, acc[j][mi]);
        acc[j][mi] = mfma_bf16(al[mi], bh, acc[j][mi]);
        acc[j][mi] = mfma_bf16(ah[mi], bh, acc[j][mi]);
      }
    }
  }
  __syncthreads();   // b1: X reads done; A free for K, B free for Q

  // E1: +bias, split hi/lo; Q -> B, K -> A (b16 scatter, [l][d] layout for frag reads)
  {
    const float bq = in_proj_b[w * 16 + ln];
    const float bk = in_proj_b[128 + w * 16 + ln];
    const int d = w * 16 + ln;
#pragma unroll
    for (int mi = 0; mi < 4; mi++)
#pragma unroll
      for (int r = 0; r < 4; r++) {
        const int l = mi * 16 + hg * 4 + r;
        const int idx = (l * 136 + d) * 2;
        const float vq = acc[0][mi][r] + bq;
        const unsigned short hq = f2bf(vq);
        *(unsigned short*)(smem + B_OFF + idx) = hq;
        *(unsigned short*)(smem + B_OFF + 17408 + idx) = f2bf(vq - bf2f(hq));
        const float vk = acc[1][mi][r] + bk;
        const unsigned short hk = f2bf(vk);
        *(unsigned short*)(smem + A_OFF + idx) = hk;
        *(unsigned short*)(smem + A_OFF + 17408 + idx) = f2bf(vk - bf2f(hk));
      }
  }
  __syncthreads();   // b2: Q,K complete

  // E2: preload K-frags (A) and Q-frags (B) to registers
  const int h   = w >> 1;                     // head
  const int mi0 = (w & 1) * 2;                // mi-half
  short8 kbh[4], kbl[4], qah[2], qal[2];
#pragma unroll
  for (int n2 = 0; n2 < 4; n2++) {
    const int idx = ((n2 * 16 + ln) * 136 + h * 32 + hg * 8) * 2;
    kbh[n2] = *(const short8*)(smem + A_OFF + idx);
    kbl[n2] = *(const short8*)(smem + A_OFF + 17408 + idx);
  }
#pragma unroll
  for (int m = 0; m < 2; m++) {
    const int idx = (((mi0 + m) * 16 + ln) * 136 + h * 32 + hg * 8) * 2;
    qah[m] = *(const short8*)(smem + B_OFF + idx);
    qal[m] = *(const short8*)(smem + B_OFF + 17408 + idx);
  }
  __syncthreads();   // b3: Q/K reads done; B free for VT

  // E3: V^T -> B (pk-paired b32 writes; per head [32 d][72 l], row stride 144B)
  {
    const float bv = in_proj_b[256 + w * 16 + ln];
    const int dv = w * 16 + ln;
    char* vth = smem + B_OFF + (dv >> 5) * 4608 + (dv & 31) * 144;
    char* vtl = vth + 18432;
#pragma unroll
    for (int mi = 0; mi < 4; mi++) {
      const float v0 = acc[2][mi][0] + bv, v1 = acc[2][mi][1] + bv;
      const float v2 = acc[2][mi][2] + bv, v3 = acc[2][mi][3] + bv;
      const unsigned short h0 = f2bf(v0), h1 = f2bf(v1);
      const unsigned short h2 = f2bf(v2), h3 = f2bf(v3);
      const int lb = (mi * 16 + hg * 4) * 2;  // byte offset of l within row
      *(unsigned*)(vth + lb)     = (unsigned)h0 | ((unsigned)h1 << 16);
      *(unsigned*)(vth + lb + 4) = (unsigned)h2 | ((unsigned)h3 << 16);
      *(unsigned*)(vtl + lb)     = pk2(v0 - bf2f(h0), v1 - bf2f(h1));
      *(unsigned*)(vtl + lb + 4) = pk2(v2 - bf2f(h2), v3 - bf2f(h3));
    }
  }
  __syncthreads();   // b4: VT complete

  // E4: preload VT-frags to registers
  short8 vbh[2][2], vbl[2][2];
#pragma unroll
  for (int ni = 0; ni < 2; ni++)
#pragma unroll
    for (int k2 = 0; k2 < 2; k2++) {
      const int idx = h * 4608 + (ni * 16 + ln) * 144 + (k2 * 32 + hg * 8) * 2;
      vbh[ni][k2] = *(const short8*)(smem + B_OFF + idx);
      vbl[ni][k2] = *(const short8*)(smem + B_OFF + 18432 + idx);
    }
  __syncthreads();   // b5: all VT reads done; A free for P, B free for O

  // ---------------- Phase 3: attention, swapped QK^T (s = K x Q) ----------------
  // s[n2][r]: q = mi*16 + ln (lane-local row!), k = n2*16 + hg*4 + r
  char* ph = smem + A_OFF + w * 4608;         // P_hi [16 q][36 uint], 144B row stride
  char* pl = ph + 2304;                       // P_lo
#pragma unroll
  for (int m = 0; m < 2; m++) {
    const int mi = mi0 + m;
    floatx4 s[4];
#pragma unroll
    for (int n2 = 0; n2 < 4; n2++) {
      s[n2] = mfma_bf16(kbh[n2], qal[m], z4);
      s[n2] = mfma_bf16(kbl[n2], qah[m], s[n2]);
      s[n2] = mfma_bf16(kbh[n2], qah[m], s[n2]);
      s[n2] = s[n2] * ATTN_SCALE;
    }
    // softmax over k: 16 in-reg values + 2 cross-hg shuffles
    float mx = fmaxf(fmaxf(s[0][0], s[0][1]), fmaxf(s[0][2], s[0][3]));
    mx = fmaxf(mx, fmaxf(fmaxf(s[1][0], s[1][1]), fmaxf(s[1][2], s[1][3])));
    mx = fmaxf(mx, fmaxf(fmaxf(s[2][0], s[2][1]), fmaxf(s[2][2], s[2][3])));
    mx = fmaxf(mx, fmaxf(fmaxf(s[3][0], s[3][1]), fmaxf(s[3][2], s[3][3])));
    mx = fmaxf(mx, __shfl_xor(mx, 16));
    mx = fmaxf(mx, __shfl_xor(mx, 32));
    float sum = 0.f;
#pragma unroll
    for (int n2 = 0; n2 < 4; n2++)
#pragma unroll
      for (int r = 0; r < 4; r++) {
        const float e = exp2f((s[n2][r] - mx) * LOG2E);
        s[n2][r] = e;
        sum += e;
      }
    sum += __shfl_xor(sum, 16);
    sum += __shfl_xor(sum, 32);
    const float inv = 1.0f / sum;
    // P hi/lo pk-paired along k -> per-wave scratch in A
#pragma unroll
    for (int n2 = 0; n2 < 4; n2++) {
      const float p0 = s[n2][0] * inv, p1 = s[n2][1] * inv;
      const float p2 = s[n2][2] * inv, p3 = s[n2][3] * inv;
      const unsigned short h0 = f2bf(p0), h1 = f2bf(p1);
      const unsigned short h2 = f2bf(p2), h3 = f2bf(p3);
      const int cb = ln * 144 + (n2 * 8 + hg * 2) * 4;   // byte offset of uint col
      *(unsigned*)(ph + cb)     = (unsigned)h0 | ((unsigned)h1 << 16);
      *(unsigned*)(ph + cb + 4) = (unsigned)h2 | ((unsigned)h3 << 16);
      *(unsigned*)(pl + cb)     = pk2(p0 - bf2f(h0), p1 - bf2f(h1));
      *(unsigned*)(pl + cb + 4) = pk2(p2 - bf2f(h2), p3 - bf2f(h3));
    }
    short8 pah[2], pal[2];
#pragma unroll
    for (int k2 = 0; k2 < 2; k2++) {
      const int off = ln * 144 + k2 * 64 + hg * 16;
      pah[k2] = *(const short8*)(ph + off);
      pal[k2] = *(const short8*)(pl + off);
    }
    floatx4 oacc[2];
    oacc[0] = z4; oacc[1] = z4;
#pragma unroll
    for (int ni = 0; ni < 2; ni++)
#pragma unroll
      for (int k2 = 0; k2 < 2; k2++) {
        oacc[ni] = mfma_bf16(pal[k2], vbh[ni][k2], oacc[ni]);
        oacc[ni] = mfma_bf16(pah[k2], vbl[ni][k2], oacc[ni]);
        oacc[ni] = mfma_bf16(pah[k2], vbh[ni][k2], oacc[ni]);
      }
    // O hi/lo -> B ([l][d] layout for phase-4 frag reads)
#pragma unroll
    for (int ni = 0; ni < 2; ni++)
#pragma unroll
      for (int r = 0; r < 4; r++) {
        const int l = mi * 16 + hg * 4 + r;
        const int d = h * 32 + ni * 16 + ln;
        const int idx = (l * 136 + d) * 2;
        const float v = oacc[ni][r];
        const unsigned short hv = f2bf(v);
        *(unsigned short*)(smem + B_OFF + idx) = hv;
        *(unsigned short*)(smem + B_OFF + 17408 + idx) = f2bf(v - bf2f(hv));
      }
  }
  __syncthreads();   // b6: O complete

  // ---------------- Phase 4: Y = (Oh+Ol) @ (Wh+Wl)^T, +bias, *gamma, store -------------
  floatx4 y[4];
#pragma unroll
  for (int mi = 0; mi < 4; mi++) y[mi] = z4;
#pragma unroll
  for (int kk = 0; kk < 4; kk++) {
    short8 oh[4], ol[4];
#pragma unroll
    for (int mi = 0; mi < 4; mi++) {
      const int idx = ((mi * 16 + ln) * 136 + kk * 32 + hg * 8) * 2;
      oh[mi] = *(const short8*)(smem + B_OFF + idx);
      ol[mi] = *(const short8*)(smem + B_OFF + 17408 + idx);
    }
    const int widx = (w * 16 + ln) * 128 + kk * 32 + hg * 8;
    short8 wbh = *(const short8*)(wout_h + widx);
    short8 wbl = *(const short8*)(wout_l + widx);
#pragma unroll
    for (int mi = 0; mi < 4; mi++) {
      y[mi] = mfma_bf16(ol[mi], wbh, y[mi]);
      y[mi] = mfma_bf16(oh[mi], wbl, y[mi]);
      y[mi] = mfma_bf16(oh[mi], wbh, y[mi]);
    }
  }
  {
    const int d = w * 16 + ln;
    const float bo = out_proj_b[d];
    const float g = gamma[d];
#pragma unroll
    for (int mi = 0; mi < 4; mi++)
#pragma unroll
      for (int r = 0; r < 4; r++) {
        const int l = mi * 16 + hg * 4 + r;
        const int py = l >> 3, px = l & 7;
        out[gbase + (size_t)(py * 256 + px) * 128 + d] = (y[mi][r] + bo) * g;
      }
  }
}

extern "C" void kernel_launch(void* const* d_in, const int* in_sizes, int n_in,
                              void* d_out, int out_size, void* d_ws, size_t ws_size,
                              hipStream_t stream) {
  const float* x     = (const float*)d_in[0];
  const float* ln_w  = (const float*)d_in[1];
  const float* ln_b  = (const float*)d_in[2];
  const float* ipw   = (const float*)d_in[3];
  const float* ipb   = (const float*)d_in[4];
  const float* opw   = (const float*)d_in[5];
  const float* opb   = (const float*)d_in[6];
  const float* gamma = (const float*)d_in[7];
  unsigned short* wbf = (unsigned short*)d_ws;

  convert_weights<<<256, 256, 0, stream>>>(ipw, opw, wbf);
  attn_kernel<<<8192, 512, 0, stream>>>(x, ln_w, ln_b, ipb, opb, gamma,
                                        wbf, wbf + 65536,          // wqkv hi/lo
                                        wbf + 49152, wbf + 114688, // wout hi/lo
                                        (float*)d_out);
}